// Round 10
// baseline (207.115 us; speedup 1.0000x reference)
//
#include <hip/hip_runtime.h>

// GridSamplePScan: out[b,t,c] = sum_{k<=t} bilinear(images[b,k,c], base_grid + (cum[t]-cum[k]))
// B=2, L=24, C=16, H=W=64 fp32. align_corners=False, zero pad, x wrapped into [-1,1).
//
// R7 (fourth submission; three infra failures, never measured): channels-FIRST gathers
// from the ORIGINAL images layout (no transpose).
//   - Each scalar gather instruction: 64 lanes x 4B near-consecutive -> ~5 cache lines
//     (vs 64 lines/instr for channels-last float4: 3x less TA/L1 work).
//   - All 64 loads of a k-step (4 corners x 16 ch) issued into local arrays before any
//     FMA -> MLP=64. __launch_bounds__(64, 2) raises VGPR cap to ~256 so the batch fits
//     (R6 failed here: default budget forced VGPR=36, serializing loads).
//   - XCD y-banding kept from R6 (FETCH dropped 51->28 MB): bid&7 = y%8.
//   - Two-pass ascending cum (bit-matches jnp.cumsum); flow[k+1] prefetched first.

#define BB 2
#define LL 24
#define CC 16
#define HH 64
#define WW 64
#define HW (HH * WW)

__device__ __forceinline__ void bilin_coords(
    float gxv0, float gyv,
    int& i00, int& i10, int& i01, int& i11,
    float& w00, float& w10, float& w01, float& w11)
{
    // wrap x into [-1,1): remainder(gxv0+1, 2) - 1; exact fmod for |v|<4
    const float v = gxv0 + 1.0f;
    float r = v - 2.0f * truncf(v * 0.5f);
    r = (r < 0.0f) ? (r + 2.0f) : r;
    const float gxv = r - 1.0f;

    const float ix = (gxv + 1.0f) * 32.0f - 0.5f;
    const float iy = (gyv + 1.0f) * 32.0f - 0.5f;

    const float x0f = floorf(ix);
    const float y0f = floorf(iy);
    const float x1f = x0f + 1.0f;
    const float y1f = y0f + 1.0f;

    const float wx1 = ix - x0f, wx0 = 1.0f - wx1;
    const float wy1 = iy - y0f, wy0 = 1.0f - wy1;

    const bool vx0 = (x0f >= 0.0f) && (x0f <= 63.0f);
    const bool vx1 = (x1f >= 0.0f) && (x1f <= 63.0f);
    const bool vy0 = (y0f >= 0.0f) && (y0f <= 63.0f);
    const bool vy1 = (y1f >= 0.0f) && (y1f <= 63.0f);

    const int x0 = min(max((int)x0f, 0), WW - 1);
    const int x1 = min(max((int)x1f, 0), WW - 1);
    const int y0 = min(max((int)y0f, 0), HH - 1);
    const int y1 = min(max((int)y1f, 0), HH - 1);

    w00 = (vx0 && vy0) ? (wx0 * wy0) : 0.0f;
    w10 = (vx1 && vy0) ? (wx1 * wy0) : 0.0f;
    w01 = (vx0 && vy1) ? (wx0 * wy1) : 0.0f;
    w11 = (vx1 && vy1) ? (wx1 * wy1) : 0.0f;

    i00 = y0 * WW + x0;
    i10 = y0 * WW + x1;
    i01 = y1 * WW + x0;
    i11 = y1 * WW + x1;
}

__global__ __launch_bounds__(64, 2) void gsps_cf(
    const float* __restrict__ flows,   // [B,L,2,H,W]
    const float* __restrict__ images,  // [B,L,C,H,W]
    float* __restrict__ out)           // [B,L,C,H,W]
{
    // bid layout: y%8 in bid&7 -> each XCD (round-robin bid%8) keeps a ~1MB y-band in L2
    const int bid = blockIdx.x;
    const int y_lo = bid & 7;
    const int r1 = bid >> 3;                 // [0, 384)
    const int t = (LL - 1) - (r1 % LL);      // big-t first within each XCD stripe
    const int r2 = r1 / LL;                  // [0, 16)
    const int y = ((r2 & 7) << 3) | y_lo;
    const int b = r2 >> 3;
    const int x = threadIdx.x;               // one wave = one row

    const float gx = -0.984375f + (float)x * 0.03125f;
    const float gy = -0.984375f + (float)y * 0.03125f;
    const int pix = y * WW + x;
    const float* fb = flows + (size_t)b * LL * 2 * HW + pix;

    // pass 1: cum[t] in ascending sequential order (bit-matches jnp.cumsum)
    float ctx = 0.0f, cty = 0.0f;
    for (int i = 0; i <= t; ++i) {
        ctx += fb[(size_t)(2 * i) * HW];
        cty += fb[(size_t)(2 * i + 1) * HW];
    }

    float acc[CC];
#pragma unroll
    for (int c = 0; c < CC; ++c) acc[c] = 0.0f;

    float cx = 0.0f, cy = 0.0f;
    float fkx = fb[0], fky = fb[HW];         // flow[0]

    for (int k = 0; k <= t; ++k) {
        cx += fkx; cy += fky;                // cum[k]
        // prefetch flow[k+1]: issued before the gather batch, consumed next iter
        if (k < t) {
            fkx = fb[(size_t)(2 * (k + 1)) * HW];
            fky = fb[(size_t)(2 * (k + 1) + 1) * HW];
        }

        int i00, i10, i01, i11;
        float w00, w10, w01, w11;
        bilin_coords(gx + (ctx - cx), gy + (cty - cy), i00, i10, i01, i11, w00, w10, w01, w11);

        const float* plane = images + ((size_t)(b * LL + k) * CC) * HW;

        // issue ALL 64 gathers (4 corners x 16 channels) before any FMA: MLP=64.
        float v00[CC], v10[CC], v01[CC], v11[CC];
#pragma unroll
        for (int c = 0; c < CC; ++c) v00[c] = plane[(size_t)c * HW + i00];
#pragma unroll
        for (int c = 0; c < CC; ++c) v10[c] = plane[(size_t)c * HW + i10];
#pragma unroll
        for (int c = 0; c < CC; ++c) v01[c] = plane[(size_t)c * HW + i01];
#pragma unroll
        for (int c = 0; c < CC; ++c) v11[c] = plane[(size_t)c * HW + i11];

#pragma unroll
        for (int c = 0; c < CC; ++c)
            acc[c] += v00[c] * w00 + v10[c] * w10 + v01[c] * w01 + v11[c] * w11;
    }

    float* o = out + ((size_t)(b * LL + t) * CC) * HW + pix;
#pragma unroll
    for (int c = 0; c < CC; ++c) o[(size_t)c * HW] = acc[c];
}

extern "C" void kernel_launch(void* const* d_in, const int* in_sizes, int n_in,
                              void* d_out, int out_size, void* d_ws, size_t ws_size,
                              hipStream_t stream) {
    const float* flows  = (const float*)d_in[0];   // [B,L,2,H,W]
    const float* images = (const float*)d_in[1];   // [B,L,C,H,W]
    float* out = (float*)d_out;                    // [B,L,C,H,W]

    const int nblk = BB * LL * HH;                 // 3072 blocks x 64 threads
    gsps_cf<<<nblk, 64, 0, stream>>>(flows, images, out);
}